// Round 5
// baseline (240.726 us; speedup 1.0000x reference)
//
#include <hip/hip_runtime.h>
#include <hip/hip_bf16.h>

typedef __attribute__((ext_vector_type(8))) short bf16x8;
typedef __attribute__((ext_vector_type(4))) float f32x4;

#define LOG2E 1.4426950408889634f

__device__ __forceinline__ ushort f2bf(float f) {
    return __builtin_bit_cast(ushort, __float2bfloat16(f));
}

__global__ __launch_bounds__(512, 8)
void attn_fused(const float* __restrict__ full,
                const float* __restrict__ last,
                const float* __restrict__ W1w, const float* __restrict__ W1b,
                const float* __restrict__ W2w, const float* __restrict__ W2b,
                const float* __restrict__ Vw,  const float* __restrict__ Vb,
                float* __restrict__ out, int T)
{
    // W2 bf16 fragments pre-packed in per-lane MFMA layout:
    // fragment f = (ot*2+kc)*64 + lane holds W2[ot*16+(lane&15)][kc*32+(lane>>4)*8 + 0..7]
    __shared__ ushort w2f[512][8];      // 8 KB, lane-linear ds_read_b128
    __shared__ float qpart[8][64];
    __shared__ float qt[64];
    __shared__ float vsh[64];
    __shared__ float accbuf[8][64];
    __shared__ float lbuf[8];

    const int b    = blockIdx.x;
    const int tid  = threadIdx.x;
    const int lane = tid & 63;
    const int wv   = tid >> 6;          // wave 0..7
    const int col  = lane & 15;
    const int grp  = lane >> 4;
    const int koff = grp * 8;

    // ---------------- stage 0 ----------------
    {
        // q~ partial: wave pg covers d in [pg*8, pg*8+8)
        const float4* lr = reinterpret_cast<const float4*>(last + (size_t)b * 64 + wv * 8);
        const float4* wr = reinterpret_cast<const float4*>(W1w + (size_t)lane * 64 + wv * 8);
        float4 a0 = lr[0], a1 = lr[1], w0 = wr[0], w1 = wr[1];
        float s = 0.f;
        s = fmaf(a0.x, w0.x, s); s = fmaf(a0.y, w0.y, s);
        s = fmaf(a0.z, w0.z, s); s = fmaf(a0.w, w0.w, s);
        s = fmaf(a1.x, w1.x, s); s = fmaf(a1.y, w1.y, s);
        s = fmaf(a1.z, w1.z, s); s = fmaf(a1.w, w1.w, s);
        qpart[wv][lane] = s;

        // one W2 fragment per thread
        int ot = tid >> 7, kc = (tid >> 6) & 1;
        const float* wp = W2w + (size_t)(ot * 16 + col) * 64 + kc * 32 + koff;
        float4 x0 = *reinterpret_cast<const float4*>(wp);
        float4 x1 = *reinterpret_cast<const float4*>(wp + 4);
        ushort* dst = w2f[tid];
        dst[0]=f2bf(x0.x); dst[1]=f2bf(x0.y); dst[2]=f2bf(x0.z); dst[3]=f2bf(x0.w);
        dst[4]=f2bf(x1.x); dst[5]=f2bf(x1.y); dst[6]=f2bf(x1.z); dst[7]=f2bf(x1.w);

        if (tid < 64) vsh[tid] = Vw[tid];
    }
    __syncthreads();
    if (tid < 64) {
        float s = W1b[tid] + W2b[tid];
        #pragma unroll
        for (int w = 0; w < 8; ++w) s += qpart[w][tid];
        qt[tid] = s;
    }
    __syncthreads();

    float q2[4], vm2[4], sv = 0.f;
    #pragma unroll
    for (int ot = 0; ot < 4; ++ot) {
        float v = vsh[ot * 16 + col];
        vm2[ot] = -2.f * v;
        sv += v;
        q2[ot] = qt[ot * 16 + col] * (2.f * LOG2E);
    }
    const float vbl = Vb[0] * LOG2E;

    const int ntile = T / (8 * 16);                 // 16 tiles per wave
    const float* base = full + ((size_t)b * T + (size_t)wv * ntile * 16) * 64;
    const ushort* wfbase = &w2f[0][0] + lane * 8;   // + (ot*2+kc)*512 shorts

    float acc = 0.f, l = 0.f;                       // acc: lane owns d = lane

    for (int t = 0; t < ntile; ++t) {
        const float* xr = base + (size_t)(t * 16 + col) * 64 + koff;
        f32x4 a00 = *reinterpret_cast<const f32x4*>(xr);
        f32x4 a01 = *reinterpret_cast<const f32x4*>(xr + 4);
        f32x4 a10 = *reinterpret_cast<const f32x4*>(xr + 32);
        f32x4 a11 = *reinterpret_cast<const f32x4*>(xr + 36);

        bf16x8 af0, af1;
        af0[0]=f2bf(a00[0]); af0[1]=f2bf(a00[1]); af0[2]=f2bf(a00[2]); af0[3]=f2bf(a00[3]);
        af0[4]=f2bf(a01[0]); af0[5]=f2bf(a01[1]); af0[6]=f2bf(a01[2]); af0[7]=f2bf(a01[3]);
        af1[0]=f2bf(a10[0]); af1[1]=f2bf(a10[1]); af1[2]=f2bf(a10[2]); af1[3]=f2bf(a10[3]);
        af1[4]=f2bf(a11[0]); af1[5]=f2bf(a11[1]); af1[6]=f2bf(a11[2]); af1[7]=f2bf(a11[3]);

        float hv[4] = {sv, sv, sv, sv};
        #pragma unroll
        for (int ot = 0; ot < 4; ++ot) {
            bf16x8 b0 = *reinterpret_cast<const bf16x8*>(wfbase + (ot * 2 + 0) * 512);
            bf16x8 b1 = *reinterpret_cast<const bf16x8*>(wfbase + (ot * 2 + 1) * 512);
            f32x4 dd = {0.f, 0.f, 0.f, 0.f};
            dd = __builtin_amdgcn_mfma_f32_16x16x32_bf16(af0, b0, dd, 0, 0, 0);
            dd = __builtin_amdgcn_mfma_f32_16x16x32_bf16(af1, b1, dd, 0, 0, 0);
            #pragma unroll
            for (int r = 0; r < 4; ++r) {
                float e  = exp2f(fmaf(dd[r], 2.f * LOG2E, q2[ot]));
                float rc = __builtin_amdgcn_rcpf(e + 1.f);
                hv[r] = fmaf(vm2[ot], rc, hv[r]);
            }
        }

        #pragma unroll
        for (int msk = 1; msk <= 8; msk <<= 1)
            #pragma unroll
            for (int r = 0; r < 4; ++r)
                hv[r] += __shfl_xor(hv[r], msk);

        float p4[4];
        #pragma unroll
        for (int r = 0; r < 4; ++r)
            p4[r] = exp2f(fmaf(hv[r], LOG2E, vbl));

        l += (p4[0] + p4[1]) + (p4[2] + p4[3]);

        // PV: acc[d=lane] += p_t * x[t,d]; p_t uniform within group (t>>2)
        const float* xcp = base + (size_t)t * 1024 + lane;
        #pragma unroll
        for (int tt = 0; tt < 16; ++tt) {
            float pt = __uint_as_float(
                __builtin_amdgcn_readlane(__float_as_uint(p4[tt & 3]), (tt >> 2) * 16));
            acc = fmaf(pt, xcp[(size_t)tt * 64], acc);
        }
    }

    // ---------------- end reductions ----------------
    l += __shfl_xor(l, 16);
    l += __shfl_xor(l, 32);

    accbuf[wv][lane] = acc;
    if (lane == 0) lbuf[wv] = l;
    __syncthreads();

    if (tid < 64) {
        float L = 0.f, a = 0.f;
        #pragma unroll
        for (int w = 0; w < 8; ++w) {
            L += lbuf[w];
            a += accbuf[w][tid];
        }
        out[(size_t)b * 64 + tid] = a / L;
    }
}

extern "C" void kernel_launch(void* const* d_in, const int* in_sizes, int n_in,
                              void* d_out, int out_size, void* d_ws, size_t ws_size,
                              hipStream_t stream) {
    const float* full = (const float*)d_in[0];
    const float* last = (const float*)d_in[1];
    const float* W1w  = (const float*)d_in[2];
    const float* W1b  = (const float*)d_in[3];
    const float* W2w  = (const float*)d_in[4];
    const float* W2b  = (const float*)d_in[5];
    const float* Vw   = (const float*)d_in[6];
    const float* Vb   = (const float*)d_in[7];
    float* out = (float*)d_out;

    const int Bn = in_sizes[1] / 64;              // 1024
    const int T  = in_sizes[0] / in_sizes[1];     // 2048

    attn_fused<<<Bn, 512, 0, stream>>>(full, last, W1w, W1b, W2w, W2b, Vw, Vb, out, T);
}